// Round 11
// baseline (400.813 us; speedup 1.0000x reference)
//
#include <hip/hip_runtime.h>

#define N_NODES  50000
#define N_EDGES  600000
#define DIM      128
#define N_GRAPHS 128
#define N_CLASSES 10
#define NB_SCAN  196          // ceil(50000/256)
#define LDSW     136          // padded LDS row width in ushorts
#define NZB      8204         // zero blocks: ceil(2100000/256)

// NOTE: harness delivers ALL integer inputs as int32 (const int*).

typedef __bf16 bf16x8 __attribute__((ext_vector_type(8)));
typedef float  f32x4  __attribute__((ext_vector_type(4)));

__device__ inline unsigned short f2bf(float f) {      // RNE float->bf16
  union { float f; unsigned int i; } u; u.f = f;
  unsigned int r = u.i + 0x7fff + ((u.i >> 16) & 1);
  return (unsigned short)(r >> 16);
}
__device__ inline float bf2f(unsigned short s) {
  union { unsigned int i; float f; } u; u.i = ((unsigned int)s) << 16;
  return u.f;
}
__device__ inline bf16x8 pack8(float4 lo, float4 hi) {
  union { bf16x8 v; unsigned short s[8]; } u;
  u.s[0] = f2bf(lo.x); u.s[1] = f2bf(lo.y); u.s[2] = f2bf(lo.z); u.s[3] = f2bf(lo.w);
  u.s[4] = f2bf(hi.x); u.s[5] = f2bf(hi.y); u.s[6] = f2bf(hi.z); u.s[7] = f2bf(hi.w);
  return u.v;
}

// ---------------- prep: zero CSR scratch + pack weights (fused) ----------------
// blocks [0,NZB): zero deg+cnt+csrc+enorm (2,100,000 words, contiguous).
// blocks [NZB, NZB+64): pack 8 matrices into MFMA B-fragment layout, bf16.

__global__ __launch_bounds__(256) void k_prep(float* __restrict__ zbase,
                                              const float* __restrict__ W1,
                                              const float* __restrict__ R1,
                                              const float* __restrict__ Wc,
                                              const float* __restrict__ Rc,
                                              unsigned short* __restrict__ pk) {
  if (blockIdx.x < NZB) {
    int i = blockIdx.x * 256 + threadIdx.x;
    if (i < 2100000) zbase[i] = 0.f;
    return;
  }
  int pb = blockIdx.x - NZB;            // 0..63
  int mm = pb >> 3, sub = pb & 7;
  const float* src = (mm == 0) ? W1
                   : (mm < 4)  ? Wc + (size_t)(mm - 1) * DIM * DIM
                   : (mm == 4) ? R1
                               : Rc + (size_t)(mm - 5) * DIM * DIM;
  int idx = sub * 256 + threadIdx.x;    // 0..2047 fragment-lane slots
  int lane = idx & 63;
  int kc   = (idx >> 6) & 3;
  int nt   = idx >> 8;
  int col  = nt * 16 + (lane & 15);
  int k0   = kc * 32 + (lane >> 4) * 8;
  unsigned short* dst = pk + (size_t)mm * 16384 + (size_t)idx * 8;
  ushort4 u;
  u.x = f2bf(src[(k0 + 0) * DIM + col]);
  u.y = f2bf(src[(k0 + 1) * DIM + col]);
  u.z = f2bf(src[(k0 + 2) * DIM + col]);
  u.w = f2bf(src[(k0 + 3) * DIM + col]);
  *(ushort4*)&dst[0] = u;
  u.x = f2bf(src[(k0 + 4) * DIM + col]);
  u.y = f2bf(src[(k0 + 5) * DIM + col]);
  u.z = f2bf(src[(k0 + 6) * DIM + col]);
  u.w = f2bf(src[(k0 + 7) * DIM + col]);
  *(ushort4*)&dst[4] = u;
}

// ---------------- CSR build (padded: per-node degree rounded up to x8) --------
// Padding slots keep src=0, w=0 (zeroed by k_prep): the 8-wide gather loops
// read node 0's row for pad slots -> L1-hit, contributes 0.

__global__ __launch_bounds__(256) void k_deg(const int* __restrict__ ei,
                                             int* __restrict__ deg) {
  int e = blockIdx.x * 256 + threadIdx.x;
  if (e < N_EDGES) atomicAdd(&deg[ei[N_EDGES + e]], 1);
}

// dinv + per-block padded-degree sum (fused)
__global__ __launch_bounds__(256) void k_dinvsum(const int* __restrict__ deg,
                                                 float* __restrict__ dinv,
                                                 int* __restrict__ bsum) {
  int i = blockIdx.x * 256 + threadIdx.x;
  int t = threadIdx.x;
  int d = (i < N_NODES) ? deg[i] : 0;
  if (i < N_NODES) dinv[i] = (d > 0) ? rsqrtf((float)d) : 0.f;
  int dp = (d + 7) & ~7;
  __shared__ int tmp[256];
  tmp[t] = dp;
  __syncthreads();
  for (int off = 128; off > 0; off >>= 1) {
    if (t < off) tmp[t] += tmp[t + off];
    __syncthreads();
  }
  if (t == 0) bsum[blockIdx.x] = tmp[0];
}

__global__ __launch_bounds__(256) void k_bscan(const int* __restrict__ bsum,
                                               int* __restrict__ boff,
                                               int* __restrict__ rowp) {
  int t = threadIdx.x;
  int v = (t < NB_SCAN) ? bsum[t] : 0;
  __shared__ int tmp[256];
  tmp[t] = v;
  __syncthreads();
  for (int off = 1; off < 256; off <<= 1) {
    int add = (t >= off) ? tmp[t - off] : 0;
    __syncthreads();
    tmp[t] += add;
    __syncthreads();
  }
  boff[t] = tmp[t] - v;          // exclusive
  if (t == 255) rowp[N_NODES] = tmp[255];   // total padded edge count
}

__global__ __launch_bounds__(256) void k_rowp(const int* __restrict__ deg,
                                              const int* __restrict__ boff,
                                              int* __restrict__ rowp) {
  int i = blockIdx.x * 256 + threadIdx.x;
  int t = threadIdx.x;
  int dp = (i < N_NODES) ? ((deg[i] + 7) & ~7) : 0;
  __shared__ int tmp[256];
  tmp[t] = dp;
  __syncthreads();
  for (int off = 1; off < 256; off <<= 1) {
    int add = (t >= off) ? tmp[t - off] : 0;
    __syncthreads();
    tmp[t] += add;
    __syncthreads();
  }
  if (i < N_NODES) rowp[i] = boff[blockIdx.x] + tmp[t] - dp;  // exclusive
}

__global__ __launch_bounds__(256) void k_fill(const int* __restrict__ ei,
                                              const int* __restrict__ rowp,
                                              int* __restrict__ cnt,
                                              const float* __restrict__ dinv,
                                              int* __restrict__ csrc,
                                              float* __restrict__ enorm) {
  int e = blockIdx.x * 256 + threadIdx.x;
  if (e < N_EDGES) {
    int s = ei[e];
    int d = ei[N_EDGES + e];
    int p = rowp[d] + atomicAdd(&cnt[d], 1);
    csrc[p] = s;
    enorm[p] = dinv[s] * dinv[d];
  }
}

// ---------------- layer-0 MFMA dual GEMM: h0 = bf16(x@W1) ; skipb = x@R1+b1 ---
// Layouts (HW-verified): A[m=lane&15][k=(lane>>4)*8+j]; D col=lane&15,
// row=(lane>>4)*4+reg.

__global__ __launch_bounds__(256) void k_gemm0(const float* __restrict__ xf,
                                               const unsigned short* __restrict__ pkW,
                                               const unsigned short* __restrict__ pkR,
                                               const float* __restrict__ bv,
                                               unsigned short* __restrict__ hwb,
                                               unsigned short* __restrict__ skipb) {
  const int tid  = threadIdx.x;
  const int wave = tid >> 6, lane = tid & 63;
  const int m = lane & 15, q = lane >> 4;
  const int rbase = blockIdx.x * 64 + wave * 16;
  const int arow  = rbase + m;
  const bool aok  = arow < N_NODES;

  bf16x8 a[4];
#pragma unroll
  for (int kc = 0; kc < 4; ++kc) {
    float4 lo = make_float4(0.f, 0.f, 0.f, 0.f);
    float4 hi = make_float4(0.f, 0.f, 0.f, 0.f);
    if (aok) {
      lo = *(const float4*)&xf[arow * DIM + kc * 32 + q * 8];
      hi = *(const float4*)&xf[arow * DIM + kc * 32 + q * 8 + 4];
    }
    a[kc] = pack8(lo, hi);
  }

  f32x4 acc[16];
#pragma unroll
  for (int t = 0; t < 16; ++t) acc[t] = (f32x4){0.f, 0.f, 0.f, 0.f};

#pragma unroll
  for (int nt = 0; nt < 8; ++nt) {
    const unsigned short* pw = pkW + ((size_t)(nt * 4) * 64 + lane) * 8;
    const unsigned short* pr = pkR + ((size_t)(nt * 4) * 64 + lane) * 8;
#pragma unroll
    for (int kc = 0; kc < 4; ++kc) {
      bf16x8 bW = *(const bf16x8*)(pw + (size_t)kc * 64 * 8);
      acc[nt] = __builtin_amdgcn_mfma_f32_16x16x32_bf16(a[kc], bW, acc[nt], 0, 0, 0);
    }
#pragma unroll
    for (int kc = 0; kc < 4; ++kc) {
      bf16x8 bR = *(const bf16x8*)(pr + (size_t)kc * 64 * 8);
      acc[8 + nt] = __builtin_amdgcn_mfma_f32_16x16x32_bf16(a[kc], bR, acc[8 + nt], 0, 0, 0);
    }
  }

#pragma unroll
  for (int nt = 0; nt < 8; ++nt) {
    int col = nt * 16 + m;
    float bias = bv[col];
#pragma unroll
    for (int rg = 0; rg < 4; ++rg) {
      int row = rbase + q * 4 + rg;
      if (row < N_NODES) {
        hwb[row * DIM + col]   = f2bf(acc[nt][rg]);
        skipb[row * DIM + col] = f2bf(acc[8 + nt][rg] + bias);
      }
    }
  }
}

// ---------------- fused agg(l) + gemm(l+1) ------------------------------------
// Phase A: 8-wide branch-free edge loop (padded CSR, pad gathers hit row 0/L1),
// 8 independent gathers in flight per half-wave -> 2x MLP vs 4-wide (R10 was
// latency-bound: VALUBusy 20%, hbm 28%, occupancy 26%).
// Phase B: MFMA gemm on the block's 64 LDS rows.

template<bool LAST>
__global__ __launch_bounds__(256) void k_aggemm(const unsigned short* __restrict__ hin,
                                                const int* __restrict__ rowp,
                                                const int* __restrict__ csrc,
                                                const float* __restrict__ enorm,
                                                const unsigned short* __restrict__ pkW,
                                                const unsigned short* __restrict__ pkR,
                                                const float* __restrict__ bv,
                                                unsigned short* __restrict__ hout,
                                                unsigned short* __restrict__ skipb,
                                                float* __restrict__ skipf) {
  __shared__ unsigned short xs[64 * LDSW];
  const int tid = threadIdx.x;
  const int row0 = blockIdx.x * 64;

  // ---- phase A ----
  {
    int hw = tid >> 5;
    int l4 = (tid & 31) * 4;
    for (int rnd = 0; rnd < 8; ++rnd) {
      int n = row0 + rnd * 8 + hw;
      float4 acc = make_float4(0.f, 0.f, 0.f, 0.f);
      if (n < N_NODES) {
        ushort4 s = *(const ushort4*)&skipb[n * DIM + l4];
        acc = make_float4(bf2f(s.x), bf2f(s.y), bf2f(s.z), bf2f(s.w));
        int e0 = rowp[n], e1 = rowp[n + 1];
        for (int e = e0; e < e1; e += 8) {
          int4   csA = *(const int4*)&csrc[e];
          int4   csB = *(const int4*)&csrc[e + 4];
          float4 wvA = *(const float4*)&enorm[e];
          float4 wvB = *(const float4*)&enorm[e + 4];
          ushort4 u0 = *(const ushort4*)&hin[csA.x * DIM + l4];
          ushort4 u1 = *(const ushort4*)&hin[csA.y * DIM + l4];
          ushort4 u2 = *(const ushort4*)&hin[csA.z * DIM + l4];
          ushort4 u3 = *(const ushort4*)&hin[csA.w * DIM + l4];
          ushort4 u4 = *(const ushort4*)&hin[csB.x * DIM + l4];
          ushort4 u5 = *(const ushort4*)&hin[csB.y * DIM + l4];
          ushort4 u6 = *(const ushort4*)&hin[csB.z * DIM + l4];
          ushort4 u7 = *(const ushort4*)&hin[csB.w * DIM + l4];
          acc.x = fmaf(wvA.x, bf2f(u0.x), fmaf(wvA.y, bf2f(u1.x), fmaf(wvA.z, bf2f(u2.x), fmaf(wvA.w, bf2f(u3.x), acc.x))));
          acc.x = fmaf(wvB.x, bf2f(u4.x), fmaf(wvB.y, bf2f(u5.x), fmaf(wvB.z, bf2f(u6.x), fmaf(wvB.w, bf2f(u7.x), acc.x))));
          acc.y = fmaf(wvA.x, bf2f(u0.y), fmaf(wvA.y, bf2f(u1.y), fmaf(wvA.z, bf2f(u2.y), fmaf(wvA.w, bf2f(u3.y), acc.y))));
          acc.y = fmaf(wvB.x, bf2f(u4.y), fmaf(wvB.y, bf2f(u5.y), fmaf(wvB.z, bf2f(u6.y), fmaf(wvB.w, bf2f(u7.y), acc.y))));
          acc.z = fmaf(wvA.x, bf2f(u0.z), fmaf(wvA.y, bf2f(u1.z), fmaf(wvA.z, bf2f(u2.z), fmaf(wvA.w, bf2f(u3.z), acc.z))));
          acc.z = fmaf(wvB.x, bf2f(u4.z), fmaf(wvB.y, bf2f(u5.z), fmaf(wvB.z, bf2f(u6.z), fmaf(wvB.w, bf2f(u7.z), acc.z))));
          acc.w = fmaf(wvA.x, bf2f(u0.w), fmaf(wvA.y, bf2f(u1.w), fmaf(wvA.z, bf2f(u2.w), fmaf(wvA.w, bf2f(u3.w), acc.w))));
          acc.w = fmaf(wvB.x, bf2f(u4.w), fmaf(wvB.y, bf2f(u5.w), fmaf(wvB.z, bf2f(u6.w), fmaf(wvB.w, bf2f(u7.w), acc.w))));
        }
        acc.x = fmaxf(acc.x, 0.f);
        acc.y = fmaxf(acc.y, 0.f);
        acc.z = fmaxf(acc.z, 0.f);
        acc.w = fmaxf(acc.w, 0.f);
      }
      int r = rnd * 8 + hw;
      ushort4 o;
      o.x = f2bf(acc.x); o.y = f2bf(acc.y); o.z = f2bf(acc.z); o.w = f2bf(acc.w);
      *(ushort4*)&xs[r * LDSW + l4] = o;
    }
  }
  __syncthreads();

  // ---- phase B ----
  const int wave = tid >> 6, lane = tid & 63;
  const int m = lane & 15, q = lane >> 4;
  const int rbase = row0 + wave * 16;

  bf16x8 a[4];
#pragma unroll
  for (int kc = 0; kc < 4; ++kc)
    a[kc] = *(const bf16x8*)&xs[(wave * 16 + m) * LDSW + kc * 32 + q * 8];

  f32x4 acc[16];
#pragma unroll
  for (int t = 0; t < 16; ++t) acc[t] = (f32x4){0.f, 0.f, 0.f, 0.f};

#pragma unroll
  for (int nt = 0; nt < 8; ++nt) {
    const unsigned short* pw = pkW + ((size_t)(nt * 4) * 64 + lane) * 8;
    const unsigned short* pr = pkR + ((size_t)(nt * 4) * 64 + lane) * 8;
#pragma unroll
    for (int kc = 0; kc < 4; ++kc) {
      bf16x8 bW = *(const bf16x8*)(pw + (size_t)kc * 64 * 8);
      acc[nt] = __builtin_amdgcn_mfma_f32_16x16x32_bf16(a[kc], bW, acc[nt], 0, 0, 0);
    }
#pragma unroll
    for (int kc = 0; kc < 4; ++kc) {
      bf16x8 bR = *(const bf16x8*)(pr + (size_t)kc * 64 * 8);
      acc[8 + nt] = __builtin_amdgcn_mfma_f32_16x16x32_bf16(a[kc], bR, acc[8 + nt], 0, 0, 0);
    }
  }

#pragma unroll
  for (int nt = 0; nt < 8; ++nt) {
    int col = nt * 16 + m;
    float bias = bv[col];
#pragma unroll
    for (int rg = 0; rg < 4; ++rg) {
      int row = rbase + q * 4 + rg;
      if (row < N_NODES) {
        hout[row * DIM + col] = f2bf(acc[nt][rg]);
        float v = acc[8 + nt][rg] + bias;
        if (LAST) skipf[row * DIM + col] = v;
        else      skipb[row * DIM + col] = f2bf(v);
      }
    }
  }
}

// ---------------- final aggregation: dlast = relu(dlast + gather(hwb)) --------

__global__ __launch_bounds__(256) void k_aggF(const unsigned short* __restrict__ hwb,
                                              const int* __restrict__ rowp,
                                              const int* __restrict__ csrc,
                                              const float* __restrict__ enorm,
                                              float* __restrict__ actf) {
  int n = blockIdx.x * 8 + (threadIdx.x >> 5);
  if (n >= N_NODES) return;
  int l4 = (threadIdx.x & 31) * 4;
  float4 acc = *(const float4*)&actf[n * DIM + l4];
  int e0 = rowp[n], e1 = rowp[n + 1];
  for (int e = e0; e < e1; e += 8) {
    int4   csA = *(const int4*)&csrc[e];
    int4   csB = *(const int4*)&csrc[e + 4];
    float4 wvA = *(const float4*)&enorm[e];
    float4 wvB = *(const float4*)&enorm[e + 4];
    ushort4 u0 = *(const ushort4*)&hwb[csA.x * DIM + l4];
    ushort4 u1 = *(const ushort4*)&hwb[csA.y * DIM + l4];
    ushort4 u2 = *(const ushort4*)&hwb[csA.z * DIM + l4];
    ushort4 u3 = *(const ushort4*)&hwb[csA.w * DIM + l4];
    ushort4 u4 = *(const ushort4*)&hwb[csB.x * DIM + l4];
    ushort4 u5 = *(const ushort4*)&hwb[csB.y * DIM + l4];
    ushort4 u6 = *(const ushort4*)&hwb[csB.z * DIM + l4];
    ushort4 u7 = *(const ushort4*)&hwb[csB.w * DIM + l4];
    acc.x = fmaf(wvA.x, bf2f(u0.x), fmaf(wvA.y, bf2f(u1.x), fmaf(wvA.z, bf2f(u2.x), fmaf(wvA.w, bf2f(u3.x), acc.x))));
    acc.x = fmaf(wvB.x, bf2f(u4.x), fmaf(wvB.y, bf2f(u5.x), fmaf(wvB.z, bf2f(u6.x), fmaf(wvB.w, bf2f(u7.x), acc.x))));
    acc.y = fmaf(wvA.x, bf2f(u0.y), fmaf(wvA.y, bf2f(u1.y), fmaf(wvA.z, bf2f(u2.y), fmaf(wvA.w, bf2f(u3.y), acc.y))));
    acc.y = fmaf(wvB.x, bf2f(u4.y), fmaf(wvB.y, bf2f(u5.y), fmaf(wvB.z, bf2f(u6.y), fmaf(wvB.w, bf2f(u7.y), acc.y))));
    acc.z = fmaf(wvA.x, bf2f(u0.z), fmaf(wvA.y, bf2f(u1.z), fmaf(wvA.z, bf2f(u2.z), fmaf(wvA.w, bf2f(u3.z), acc.z))));
    acc.z = fmaf(wvB.x, bf2f(u4.z), fmaf(wvB.y, bf2f(u5.z), fmaf(wvB.z, bf2f(u6.z), fmaf(wvB.w, bf2f(u7.z), acc.z))));
    acc.w = fmaf(wvA.x, bf2f(u0.w), fmaf(wvA.y, bf2f(u1.w), fmaf(wvA.z, bf2f(u2.w), fmaf(wvA.w, bf2f(u3.w), acc.w))));
    acc.w = fmaf(wvB.x, bf2f(u4.w), fmaf(wvB.y, bf2f(u5.w), fmaf(wvB.z, bf2f(u6.w), fmaf(wvB.w, bf2f(u7.w), acc.w))));
  }
  acc.x = fmaxf(acc.x, 0.f);
  acc.y = fmaxf(acc.y, 0.f);
  acc.z = fmaxf(acc.z, 0.f);
  acc.w = fmaxf(acc.w, 0.f);
  *(float4*)&actf[n * DIM + l4] = acc;
}

// ---------------- global mean pool: block per graph, batch is SORTED ----------

__global__ __launch_bounds__(1024) void k_pool2(const float* __restrict__ h,
                                                const int* __restrict__ batch,
                                                float* __restrict__ pooled) {
  int g = blockIdx.x;
  int t = threadIdx.x;
  __shared__ int sb[2];
  if (t < 2) {
    int target = g + t;                 // lower_bound(batch, target)
    int lo = 0, hi = N_NODES;
    while (lo < hi) {
      int mid = (lo + hi) >> 1;
      if (batch[mid] < target) lo = mid + 1; else hi = mid;
    }
    sb[t] = lo;
  }
  __syncthreads();
  int start = sb[0], end = sb[1];
  int c = t & 127, rg = t >> 7;         // 8 row groups
  float acc = 0.f;
  for (int r = start + rg; r < end; r += 8) acc += h[r * DIM + c];
  __shared__ float sp[8][DIM];
  sp[rg][c] = acc;
  __syncthreads();
  if (rg == 0) {
    float tot = acc;
#pragma unroll
    for (int i = 1; i < 8; ++i) tot += sp[i][c];
    float cnt = fmaxf((float)(end - start), 1.f);
    pooled[g * DIM + c] = tot / cnt;
  }
}

// ---------------- MLP head ----------------

__global__ __launch_bounds__(128) void k_mlp1(const float* __restrict__ pooled,
                                              const float* __restrict__ w,
                                              const float* __restrict__ bias,
                                              float* __restrict__ g1) {
  int g = blockIdx.x, t = threadIdx.x;
  __shared__ float sp[DIM];
  sp[t] = pooled[g * DIM + t];
  __syncthreads();
  float acc = bias[t];
#pragma unroll 4
  for (int k = 0; k < DIM; ++k) acc = fmaf(sp[k], w[k * DIM + t], acc);
  g1[g * DIM + t] = fmaxf(acc, 0.f);
}

__global__ __launch_bounds__(128) void k_mlp2(const float* __restrict__ g1,
                                              const float* __restrict__ w,
                                              const float* __restrict__ bias,
                                              float* __restrict__ out) {
  int g = threadIdx.x;   // one thread per graph
  float l[N_CLASSES];
#pragma unroll
  for (int c = 0; c < N_CLASSES; ++c) l[c] = bias[c];
  for (int k = 0; k < DIM; ++k) {
    float gv = g1[g * DIM + k];
#pragma unroll
    for (int c = 0; c < N_CLASSES; ++c) l[c] = fmaf(gv, w[k * N_CLASSES + c], l[c]);
  }
  float m = l[0];
#pragma unroll
  for (int c = 1; c < N_CLASSES; ++c) m = fmaxf(m, l[c]);
  float s = 0.f;
#pragma unroll
  for (int c = 0; c < N_CLASSES; ++c) s += expf(l[c] - m);
  float lse = logf(s) + m;
#pragma unroll
  for (int c = 0; c < N_CLASSES; ++c) out[g * N_CLASSES + c] = l[c] - lse;
}

// ---------------- launch ----------------

extern "C" void kernel_launch(void* const* d_in, const int* in_sizes, int n_in,
                              void* d_out, int out_size, void* d_ws, size_t ws_size,
                              hipStream_t stream) {
  const float* x     = (const float*)d_in[0];
  const int* ei      = (const int*)d_in[1];     // int32 on device (harness)
  const int* batch   = (const int*)d_in[2];     // int32 on device (harness)
  const float* W1  = (const float*)d_in[3];
  const float* R1  = (const float*)d_in[4];
  const float* b1  = (const float*)d_in[5];
  const float* Wc  = (const float*)d_in[6];
  const float* Rc  = (const float*)d_in[7];
  const float* bc  = (const float*)d_in[8];
  const float* l1w = (const float*)d_in[9];
  const float* l1b = (const float*)d_in[10];
  const float* l2w = (const float*)d_in[11];
  const float* l2b = (const float*)d_in[12];

  float* out   = (float*)d_out;
  float* dlast = out + N_GRAPHS * N_CLASSES;   // 'last' region (fp32 layer-4 buffer)

  // workspace layout (float-word offsets), ~47.6 MB total:
  //   0         h0    (3.2M w, bf16 x 6.4M)
  //   3200000   h1    (3.2M w)
  //   6400000   skipb (3.2M w)
  //   9600000   deg   (50,000)      -- zero region start
  //   9650000   cnt   (50,000)
  //   9700000   csrc  (1,000,000)
  //   10700000  enorm (1,000,000)   -- zero region end (2,100,000 words)
  //   11700000  dinv  (50,000)
  //   11750000  rowp  (50,016)
  //   11800016  pooled(16,384)
  //   11816400  g1    (16,384)
  //   11832784  pk    (65,536 w = 131,072 ushort)
  //   11898320  bsum  (256)
  //   11898576  boff  (256)
  float* ws = (float*)d_ws;
  unsigned short* h0    = (unsigned short*)ws;
  unsigned short* h1    = (unsigned short*)(ws + 3200000);
  unsigned short* skipb = (unsigned short*)(ws + 6400000);
  int*   deg   = (int*)(ws + 9600000);
  int*   cnt   = (int*)(ws + 9650000);
  int*   csrc  = (int*)(ws + 9700000);
  float* enorm = ws + 10700000;
  float* dinv  = ws + 11700000;
  int*   rowp  = (int*)(ws + 11750000);
  float* pooled= ws + 11800016;
  float* g1    = ws + 11816400;
  unsigned short* pk = (unsigned short*)(ws + 11832784);
  int*   bsum  = (int*)(ws + 11898320);
  int*   boff  = (int*)(ws + 11898576);

  // CSR build (runs every launch; ws is re-poisoned by the harness)
  k_prep<<<NZB + 64, 256, 0, stream>>>(ws + 9600000, W1, R1, Wc, Rc, pk);
  k_deg <<<(N_EDGES + 255) / 256, 256, 0, stream>>>(ei, deg);
  k_dinvsum<<<NB_SCAN, 256, 0, stream>>>(deg, dinv, bsum);
  k_bscan<<<1, 256, 0, stream>>>(bsum, boff, rowp);
  k_rowp<<<NB_SCAN, 256, 0, stream>>>(deg, boff, rowp);
  k_fill<<<(N_EDGES + 255) / 256, 256, 0, stream>>>(ei, rowp, cnt, dinv, csrc, enorm);

  const int NGB = (N_NODES + 63) / 64;    // 782
  const int NAB = (N_NODES + 7) / 8;      // 6250

  // layer 1 gemm: x (fp32) -> h0, skipb
  k_gemm0<<<NGB, 256, 0, stream>>>(x, pk + 0 * 16384, pk + 4 * 16384, b1, h0, skipb);
  // fused [agg1 + gemm2]: h0,skipb -> h1, skipb
  k_aggemm<false><<<NGB, 256, 0, stream>>>(h0, rowp, csrc, enorm,
      pk + 1 * 16384, pk + 5 * 16384, bc + 0 * DIM, h1, skipb, nullptr);
  // fused [agg2 + gemm3]: h1,skipb -> h0, skipb
  k_aggemm<false><<<NGB, 256, 0, stream>>>(h1, rowp, csrc, enorm,
      pk + 2 * 16384, pk + 6 * 16384, bc + 1 * DIM, h0, skipb, nullptr);
  // fused [agg3 + gemm4]: h0,skipb -> h1, dlast (fp32 skip)
  k_aggemm<true><<<NGB, 256, 0, stream>>>(h0, rowp, csrc, enorm,
      pk + 3 * 16384, pk + 7 * 16384, bc + 2 * DIM, h1, skipb, dlast);
  // final agg4: dlast = relu(dlast + gather(h1))
  k_aggF<<<NAB, 256, 0, stream>>>(h1, rowp, csrc, enorm, dlast);

  k_pool2<<<N_GRAPHS, 1024, 0, stream>>>(dlast, batch, pooled);
  k_mlp1<<<N_GRAPHS, 128, 0, stream>>>(pooled, l1w, l1b, g1);
  k_mlp2<<<1, N_GRAPHS, 0, stream>>>(g1, l2w, l2b, out);
}